// Round 18
// baseline (103.812 us; speedup 1.0000x reference)
//
#include <hip/hip_runtime.h>
#include <hip/hip_fp16.h>

// Deformable Conv2d — MI355X, round 18
// vs R16: transpose kernel FUSED into dcn staging. The window is staged
// directly from x (f32 NCHW): per slot 8 coalesced dword loads (channel-
// plane stride) + cvt + one ds_write_b128. Kills the serial ~10us transpose
// dispatch and the 32MB xt write + re-read round-trip; gather hot path is
// byte-identical to R16 (best round so far: 48 VGPR, 47% occupancy).

#define KSZ 3
#define PAD 1

static constexpr int B   = 4;
static constexpr int Cin = 64;
static constexpr int H   = 256;
static constexpr int W   = 256;
static constexpr int G   = 8;
static constexpr int OC  = 64;
static constexpr int KK  = KSZ * KSZ;  // 9
static constexpr int Cpg = Cin / G;    // 8
static constexpr int OPG = OC / G;     // 8
static constexpr int HW  = H * W;
static constexpr int NXCD = 8;

static constexpr int BR    = 4;        // output rows per block
static constexpr int BC    = 64;       // output cols per block
static constexpr int MARG  = 5;
static constexpr int WROWS = BR + 2 * MARG + 1;  // 15
static constexpr int WCOLS = 75;                 // 16B slots/row
static constexpr int WUSED = BC + 2 * MARG;      // 74
static constexpr int WSLOTS = WROWS * WCOLS;     // 1125

typedef _Float16 f16x8  __attribute__((ext_vector_type(8)));
typedef float    f32x16 __attribute__((ext_vector_type(16)));

union U4H {
    uint4 u;
    __half2 h2[4];
    _Float16 h[8];
    f16x8 v;
};

// ---- prep: per-lane MFMA A-fragments, layout [g][m][lane] (40 KB) ----
__global__ __launch_bounds__(320) void prep_weights(
    const float* __restrict__ weight, uint4* __restrict__ wfrag)
{
    const int g    = blockIdx.x;
    const int tid  = threadIdx.x;     // 0..319
    const int m    = tid >> 6;        // 0..4
    const int lane = tid & 63;
    const int hi   = lane >> 5;
    const int lp   = lane & 31;
    const int t    = 2 * m + hi;
    U4H a;
#pragma unroll
    for (int c = 0; c < 8; ++c) {
        float v = 0.0f;
        if (lp < OPG && t < KK)
            v = weight[((size_t)(g * OPG + lp) * Cpg + c) * KK + t];
        a.h[c] = (_Float16)v;
    }
    wfrag[((size_t)g * 5 + m) * 64 + lane] = a.u;
}

// ---- cold path: boundary weights + f32 global gathers + blend (rare) ----
__device__ __attribute__((noinline)) f16x8 slow_sample(
    const float* __restrict__ xsrc, int y0, int x0, float wy, float wx, float ms)
{
    const bool vy0 = (unsigned)y0 < (unsigned)H;
    const bool vy1 = (unsigned)(y0 + 1) < (unsigned)H;
    const bool vx0 = (unsigned)x0 < (unsigned)W;
    const bool vx1 = (unsigned)(x0 + 1) < (unsigned)W;
    const float u  = vy0 ? (1.f - wy) * ms : 0.f;
    const float vv = vy1 ? wy * ms : 0.f;
    const float ca = vx0 ? (1.f - wx) : 0.f;
    const float cb = vx1 ? wx : 0.f;
    const float w00 = u * ca, w01 = u * cb, w10 = vv * ca, w11 = vv * cb;
    const int yc0 = min(max(y0, 0), H - 1), yc1 = min(max(y0 + 1, 0), H - 1);
    const int xc0 = min(max(x0, 0), W - 1), xc1 = min(max(x0 + 1, 0), W - 1);
    const int o00 = yc0 * W + xc0, o01 = yc0 * W + xc1;
    const int o10 = yc1 * W + xc0, o11 = yc1 * W + xc1;
    U4H s;
#pragma unroll
    for (int c = 0; c < 8; ++c) {
        const float* p = xsrc + (size_t)c * HW;
        s.h[c] = (_Float16)(w00 * p[o00] + w01 * p[o01] + w10 * p[o10] + w11 * p[o11]);
    }
    return s.v;
}

// ---- main kernel: 256 threads, 4 rows x 64 cols per block ----
__global__ __launch_bounds__(256) void dcn_kernel(
    const float* __restrict__ x,
    const uint4* __restrict__ wfrag,
    const float* __restrict__ offset,
    const float* __restrict__ mask,
    const float* __restrict__ bias,
    float* __restrict__ out)
{
    __shared__ uint4 win[WSLOTS];   // 18,000 B

    // XCD-chunked bijective swizzle (8192 blocks % 8 == 0)
    const unsigned id = blockIdx.x;
    const unsigned wl = (id & (NXCD - 1)) * (gridDim.x / NXCD) + (id >> 3);
    const int colblk = wl & 3;
    const int rowblk = (wl >> 2) & 63;
    const int g      = (wl >> 8) & (G - 1);
    const int b      = wl >> 11;

    const int h_base = rowblk * BR;
    const int xbase  = colblk * BC;
    const int h0     = h_base - MARG;
    const int x0base = xbase - MARG;

    const int tid  = threadIdx.x;
    const int lane = tid & 63;
    const int wave = tid >> 6;                // 0..3 -> output row
    const int hi   = lane >> 5;               // tap parity in MFMA k dim
    const int lp   = lane & 31;               // A-row (out ch) / B-col (pixel)

    const int h = h_base + wave;

    const float* xsrc = x + (size_t)(b * Cin + g * Cpg) * HW;  // channel-0 plane

    // ---- stage the 15x74 window straight from x (f32 -> fp16 pack);
    //      out-of-image slots get ZERO ----
#pragma unroll
    for (int it = 0; it < 5; ++it) {
        const int k = it * 256 + tid;
        if (k < WSLOTS) {
            const int i = k / WCOLS;
            const int j = k - i * WCOLS;
            const int gr = h0 + i;
            const int gc = x0base + j;
            const bool vld = ((unsigned)gr < (unsigned)H) & ((unsigned)gc < (unsigned)W);
            const int addr = min(max(gr, 0), H - 1) * W + min(max(gc, 0), W - 1);
            U4H v;
#pragma unroll
            for (int c = 0; c < 8; ++c)
                v.h[c] = (_Float16)xsrc[addr + (size_t)c * HW];  // coalesced per c
            if (!vld) v.u = make_uint4(0, 0, 0, 0);
            win[k] = v.u;
        }
    }

    const float* offy = offset + (size_t)(b * 2 + 0) * (G * KK) * HW;
    const float* offx = offset + (size_t)(b * 2 + 1) * (G * KK) * HW;
    const float* mk   = mask + (size_t)b * (G * KK) * HW;
    const uint4* wfb  = wfrag + (size_t)g * 5 * 64 + lane;

    const int pix0 = h * W + xbase + lp;
    const int pix1 = pix0 + 32;

    // ---- prologue: m=0 loads ----
    float dy0c, dx0c, mv0c, dy1c, dx1c, mv1c;
    U4H afc;
    {
        const int t0  = hi;                    // 2*0 + hi
        const int oI = (G * KK - 1 - (g * KK + t0)) * HW;
        const int mI = (g * KK + t0) * HW;
        dy0c = offy[oI + pix0];  dx0c = offx[oI + pix0];  mv0c = mk[mI + pix0];
        dy1c = offy[oI + pix1];  dx1c = offx[oI + pix1];  mv1c = mk[mI + pix1];
        afc.u = wfb[0];
    }

    __syncthreads();   // window ready

    // hot sample: 2-compare predicate, 4 window reads, packed blend
    auto sample = [&](float py, float px, float ms) -> f16x8 {
        const float y0f = floorf(py), x0f = floorf(px);
        const float wy = py - y0f, wx = px - x0f;
        const int y0 = (int)y0f, x0 = (int)x0f;
        const int iy0 = y0 - h0;
        const int ix0 = x0 - x0base;
        const bool ok = ((unsigned)iy0 <= (unsigned)(WROWS - 2)) &
                        ((unsigned)ix0 <= (unsigned)(WUSED - 2));
        int a0 = iy0 * WCOLS + ix0;
        a0 = ok ? a0 : 0;
        U4H a, bq, c, d;
        a.u  = win[a0];          bq.u = win[a0 + 1];
        c.u  = win[a0 + WCOLS];  d.u  = win[a0 + WCOLS + 1];
        const float u  = (1.f - wy) * ms;
        const float vv = wy * ms;
        const float w00 = u * (1.f - wx), w01 = u * wx;
        const float w10 = vv * (1.f - wx), w11 = vv * wx;
        const __half2 h00 = __float2half2_rn(w00);
        const __half2 h01 = __float2half2_rn(w01);
        const __half2 h10 = __float2half2_rn(w10);
        const __half2 h11 = __float2half2_rn(w11);
        U4H s;
#pragma unroll
        for (int i = 0; i < 4; ++i)
            s.h2[i] = __hfma2(h00, a.h2[i],
                      __hfma2(h01, bq.h2[i],
                      __hfma2(h10, c.h2[i],
                      __hmul2(h11, d.h2[i]))));
        f16x8 res = s.v;
        if (__builtin_expect(!__all((int)ok), 0)) {     // |offset| > ~4.5
            if (!ok) res = slow_sample(xsrc, y0, x0, wy, wx, ms);
        }
        return res;
    };

    f32x16 acc0 = {};
    f32x16 acc1 = {};

#pragma unroll 1
    for (int m = 0; m < 5; ++m) {
        // ---- issue next-iter loads (redundant re-load of m=4 on last) ----
        const int mn  = (m < 4) ? m + 1 : 4;
        const int tn  = 2 * mn + hi;
        const int ttn = (tn > 8) ? 8 : tn;
        const int oIn = (G * KK - 1 - (g * KK + ttn)) * HW;
        const int mIn = (g * KK + ttn) * HW;
        const float dy0n = offy[oIn + pix0];
        const float dx0n = offx[oIn + pix0];
        const float mv0n = mk[mIn + pix0];
        const float dy1n = offy[oIn + pix1];
        const float dx1n = offx[oIn + pix1];
        const float mv1n = mk[mIn + pix1];
        U4H afn; afn.u = wfb[mn * 64];

        // ---- compute current ----
        const int t  = 2 * m + hi;
        const int tt = (t > 8) ? 8 : t;
        const int ki = (tt >= 3) + (tt >= 6);
        const int kj = tt - 3 * ki;
        const float pyb = (float)(h - PAD + ki);
        const float pxb = (float)(xbase + lp - PAD + kj);

        float sg0 = 1.0f / (1.0f + __expf(-mv0c));
        float sg1 = 1.0f / (1.0f + __expf(-mv1c));
        sg0 = (t <= 8) ? sg0 : 0.0f;
        sg1 = (t <= 8) ? sg1 : 0.0f;

        acc0 = __builtin_amdgcn_mfma_f32_32x32x16_f16(
            afc.v, sample(pyb + dy0c, pxb + dx0c, sg0), acc0, 0, 0, 0);
        acc1 = __builtin_amdgcn_mfma_f32_32x32x16_f16(
            afc.v, sample(pyb + dy1c, pxb + 32.0f + dx1c, sg1), acc1, 0, 0, 0);

        // ---- roll ----
        dy0c = dy0n; dx0c = dx0n; mv0c = mv0n;
        dy1c = dy1n; dx1c = dx1n; mv1c = mv1n;
        afc = afn;
    }

    // C layout: col = lp (pixel), row = (reg&3) + 8*(reg>>2) + 4*hi.
    // Useful rows 0..7 -> out channel d = reg + 4*hi (regs 0..3).
#pragma unroll
    for (int tile = 0; tile < 2; ++tile) {
        const int wq = xbase + tile * 32 + lp;
#pragma unroll
        for (int r = 0; r < 4; ++r) {
            const int dd = r + 4 * hi;
            const float v = (tile == 0 ? acc0[r] : acc1[r]) + bias[g * OPG + dd];
            out[((size_t)b * OC + g * OPG + dd) * HW + h * W + wq] = v;
        }
    }
}

extern "C" void kernel_launch(void* const* d_in, const int* in_sizes, int n_in,
                              void* d_out, int out_size, void* d_ws, size_t ws_size,
                              hipStream_t stream) {
    const float* x      = (const float*)d_in[0];
    const float* offset = (const float*)d_in[1];
    const float* mask   = (const float*)d_in[2];
    const float* weight = (const float*)d_in[3];
    const float* bias   = (const float*)d_in[4];
    float* out = (float*)d_out;

    uint4* wfrag = (uint4*)d_ws;   // 40 KiB

    prep_weights<<<dim3(G), dim3(320), 0, stream>>>(weight, wfrag);
    dcn_kernel<<<dim3(B * G * (H / BR) * (W / BC)), dim3(256), 0, stream>>>(
        x, wfrag, offset, mask, bias, out);
}